// Round 1
// baseline (537.299 us; speedup 1.0000x reference)
//
#include <hip/hip_runtime.h>
#include <hip/hip_bf16.h>

#define T_SEQ 2048
#define D_IN  1024
#define DH    128

typedef __attribute__((ext_vector_type(8))) short bf16x8;   // 8 bf16 in 4 VGPRs
typedef __attribute__((ext_vector_type(4))) float f32x4;

__device__ inline short f2bf(float f) {
    union { float f; unsigned u; } a; a.f = f;
    unsigned u = a.u;
    return (short)((u + 0x7fffu + ((u >> 16) & 1u)) >> 16);   // RNE
}

// ---------------- K0: W transpose -> bf16 WT[3][128][1024] ----------------
__global__ __launch_bounds__(256) void k_wt(const float* __restrict__ Wq,
                                            const float* __restrict__ Wk,
                                            const float* __restrict__ Wv,
                                            short* __restrict__ WT) {
    int idx = blockIdx.x * 256 + threadIdx.x;           // 0 .. 3*128*1024-1
    if (idx >= 3 * DH * D_IN) return;
    int m = idx >> 17;                 // which matrix
    int n = (idx >> 10) & (DH - 1);    // output col
    int k = idx & (D_IN - 1);          // input dim
    const float* W = (m == 0) ? Wq : (m == 1) ? Wk : Wv;
    WT[idx] = f2bf(W[k * DH + n]);
}

// ---------------- K1: QKV projection GEMM (bf16 MFMA) ----------------
// Q,K row-major bf16 [B*T][128]; V stored transposed VT[b][v][t] bf16.
__global__ __launch_bounds__(256) void k_qkv(const float* __restrict__ x,
                                             const short* __restrict__ WT,
                                             const float* __restrict__ bq,
                                             const float* __restrict__ bk,
                                             const float* __restrict__ bv,
                                             short* __restrict__ Qb,
                                             short* __restrict__ Kb,
                                             short* __restrict__ VT) {
    __shared__ short wlds[384 * 72];                    // 64-k chunk of WT, padded stride 72
    int tid = threadIdx.x;
    int wv  = tid >> 6;
    int lane = tid & 63;
    int lr = lane & 15, lg = lane >> 4;
    int mbase = blockIdx.x * 64 + wv * 16;

    const f32x4 z4 = {0.f, 0.f, 0.f, 0.f};
    f32x4 acc[24];
#pragma unroll
    for (int i = 0; i < 24; i++) acc[i] = z4;

    for (int kc = 0; kc < D_IN; kc += 64) {
        __syncthreads();
        // stage WT[0:384][kc:kc+64] -> wlds (3072 x 16B chunks, 12 per thread)
        for (int c = tid; c < 3072; c += 256) {
            int row = c >> 3, part = c & 7;
            *(uint4*)&wlds[row * 72 + part * 8] =
                *(const uint4*)&WT[row * 1024 + kc + part * 8];
        }
        __syncthreads();
#pragma unroll
        for (int ks2 = 0; ks2 < 2; ks2++) {
            const float* xp = x + (size_t)(mbase + lr) * D_IN + kc + ks2 * 32 + lg * 8;
            float4 x0 = *(const float4*)xp;
            float4 x1 = *(const float4*)(xp + 4);
            bf16x8 a;
            a[0] = f2bf(x0.x); a[1] = f2bf(x0.y); a[2] = f2bf(x0.z); a[3] = f2bf(x0.w);
            a[4] = f2bf(x1.x); a[5] = f2bf(x1.y); a[6] = f2bf(x1.z); a[7] = f2bf(x1.w);
#pragma unroll
            for (int nt = 0; nt < 24; nt++) {
                bf16x8 b = *(const bf16x8*)&wlds[(nt * 16 + lr) * 72 + ks2 * 32 + lg * 8];
                acc[nt] = __builtin_amdgcn_mfma_f32_16x16x32_bf16(a, b, acc[nt], 0, 0, 0);
            }
        }
    }
    // epilogue: bias + store
#pragma unroll
    for (int nt = 0; nt < 24; nt++) {
        int n = nt * 16 + lr;
        float bias = (n < 128) ? bq[n] : (n < 256) ? bk[n - 128] : bv[n - 256];
#pragma unroll
        for (int r = 0; r < 4; r++) {
            int row = mbase + lg * 4 + r;
            short v16 = f2bf(acc[nt][r] + bias);
            if (n < 128)        Qb[(size_t)row * DH + n] = v16;
            else if (n < 256)   Kb[(size_t)row * DH + (n - 128)] = v16;
            else {
                int b = row >> 11, t = row & (T_SEQ - 1), vc = n - 256;
                VT[((size_t)b * DH + vc) * T_SEQ + t] = v16;
            }
        }
    }
}

// ---------------- K2: per-column (key j) online max / sum over q <= j ------
__global__ __launch_bounds__(256) void k_stats(const short* __restrict__ Qb,
                                               const short* __restrict__ Kb,
                                               float* __restrict__ mcol,
                                               float* __restrict__ rZcol) {
    int b = blockIdx.y;
    int wv = threadIdx.x >> 6;
    int lane = threadIdx.x & 63;
    int lr = lane & 15, lg = lane >> 4;
    int jsub = blockIdx.x * 64 + wv * 16;

    const short* Kp = Kb + ((size_t)b * T_SEQ + jsub + lr) * DH;
    bf16x8 kf[4];
#pragma unroll
    for (int ks = 0; ks < 4; ks++) kf[ks] = *(const bf16x8*)(Kp + ks * 32 + lg * 8);

    float m_run[4], Z_run[4];
#pragma unroll
    for (int r = 0; r < 4; r++) { m_run[r] = -INFINITY; Z_run[r] = 0.f; }

    const short* Qbase = Qb + (size_t)b * T_SEQ * DH;
    const f32x4 z4 = {0.f, 0.f, 0.f, 0.f};
    int nqt = jsub / 16 + 1;
    for (int qt = 0; qt < nqt; qt++) {
        f32x4 s = z4;
#pragma unroll
        for (int ks = 0; ks < 4; ks++) {
            bf16x8 qf = *(const bf16x8*)(Qbase + (size_t)(qt * 16 + lr) * DH + ks * 32 + lg * 8);
            s = __builtin_amdgcn_mfma_f32_16x16x32_bf16(kf[ks], qf, s, 0, 0, 0);
        }
        int q = qt * 16 + lr;
#pragma unroll
        for (int r = 0; r < 4; r++) {
            int j = jsub + lg * 4 + r;                // D row = j, col = q
            float sv = (q <= j) ? s[r] : -INFINITY;
            float tmax = sv;
            for (int o = 1; o < 16; o <<= 1) tmax = fmaxf(tmax, __shfl_xor(tmax, o, 16));
            float m_new = fmaxf(m_run[r], tmax);
            float p = (q <= j) ? __expf(sv - m_new) : 0.f;
            float tsum = p;
            for (int o = 1; o < 16; o <<= 1) tsum += __shfl_xor(tsum, o, 16);
            Z_run[r] = Z_run[r] * __expf(m_run[r] - m_new) + tsum;
            m_run[r] = m_new;
        }
    }
    if (lr == 0) {
#pragma unroll
        for (int r = 0; r < 4; r++) {
            int j = jsub + lg * 4 + r;
            mcol[(size_t)b * T_SEQ + j]  = m_run[r];
            rZcol[(size_t)b * T_SEQ + j] = 1.0f / Z_run[r];
        }
    }
}

// ---------------- K3: out[q][v] = sum_{j>=q} exp(s-m[j])/Z[j] * V[j][v] ----
__global__ __launch_bounds__(256) void k_out(const short* __restrict__ Qb,
                                             const short* __restrict__ Kb,
                                             const short* __restrict__ VT,
                                             const float* __restrict__ mcol,
                                             const float* __restrict__ rZcol,
                                             float* __restrict__ out) {
    __shared__ short pbuf[4][16 * 40];                 // per-wave P tile, padded stride 40
    int b = blockIdx.y;
    int qb = blockIdx.x * 64;
    int wv = threadIdx.x >> 6;
    int lane = threadIdx.x & 63;
    int lr = lane & 15, lg = lane >> 4;
    int qsub = qb + wv * 16;

    const short* Qp = Qb + ((size_t)b * T_SEQ + qsub + lr) * DH;
    bf16x8 qf[4];
#pragma unroll
    for (int ks = 0; ks < 4; ks++) qf[ks] = *(const bf16x8*)(Qp + ks * 32 + lg * 8);

    const f32x4 z4 = {0.f, 0.f, 0.f, 0.f};
    f32x4 oacc[8];
#pragma unroll
    for (int i = 0; i < 8; i++) oacc[i] = z4;

    const short* Kbase = Kb + (size_t)b * T_SEQ * DH;
    const short* VTb   = VT + (size_t)b * DH * T_SEQ;
    const float* mb = mcol + (size_t)b * T_SEQ;
    const float* zb = rZcol + (size_t)b * T_SEQ;
    short* pw = &pbuf[wv][0];

    for (int j0 = qb; j0 < T_SEQ; j0 += 32) {
#pragma unroll
        for (int half = 0; half < 2; half++) {
            int jt = j0 + half * 16;
            f32x4 s = z4;
#pragma unroll
            for (int ks = 0; ks < 4; ks++) {
                bf16x8 kfr = *(const bf16x8*)(Kbase + (size_t)(jt + lr) * DH + ks * 32 + lg * 8);
                s = __builtin_amdgcn_mfma_f32_16x16x32_bf16(qf[ks], kfr, s, 0, 0, 0);
            }
            int j = jt + lr;                           // D row = q, col = j
            float mj = mb[j], rz = zb[j];
#pragma unroll
            for (int r = 0; r < 4; r++) {
                int q = qsub + lg * 4 + r;
                float p = (j >= q) ? __expf(s[r] - mj) * rz : 0.f;
                pw[(lg * 4 + r) * 40 + half * 16 + lr] = f2bf(p);
            }
        }
        // PV: outT[v][q] += VT[v][j0:j0+32] . pT[j][q]   (same-wave LDS RAW,
        // compiler orders via lgkmcnt)
        bf16x8 bp = *(const bf16x8*)&pw[lr * 40 + lg * 8];
#pragma unroll
        for (int vt = 0; vt < 8; vt++) {
            bf16x8 av = *(const bf16x8*)(VTb + (size_t)(vt * 16 + lr) * T_SEQ + j0 + lg * 8);
            oacc[vt] = __builtin_amdgcn_mfma_f32_16x16x32_bf16(av, bp, oacc[vt], 0, 0, 0);
        }
    }
    // store: lane holds outT[v = vt*16+lg*4+r][q = qsub+lr]
#pragma unroll
    for (int vt = 0; vt < 8; vt++)
#pragma unroll
        for (int r = 0; r < 4; r++) {
            int v = vt * 16 + lg * 4 + r;
            int q = qsub + lr;
            out[((size_t)b * T_SEQ + q) * DH + v] = oacc[vt][r];
        }
}

extern "C" void kernel_launch(void* const* d_in, const int* in_sizes, int n_in,
                              void* d_out, int out_size, void* d_ws, size_t ws_size,
                              hipStream_t stream) {
    const float* x  = (const float*)d_in[0];
    const float* Wq = (const float*)d_in[1];
    const float* bq = (const float*)d_in[2];
    const float* Wk = (const float*)d_in[3];
    const float* bk = (const float*)d_in[4];
    const float* Wv = (const float*)d_in[5];
    const float* bv = (const float*)d_in[6];
    float* out = (float*)d_out;

    char* ws = (char*)d_ws;
    short* WT = (short*)ws;                                   // 786432 B
    short* Qb = (short*)(ws + 786432);                        // 4 MB
    short* Kb = (short*)(ws + 786432 + 4194304);              // 4 MB
    short* VT = (short*)(ws + 786432 + 2 * 4194304);          // 4 MB
    float* mcol = (float*)(ws + 786432 + 3 * 4194304);        // 64 KB
    float* rZ   = (float*)(ws + 786432 + 3 * 4194304 + 65536);// 64 KB

    hipLaunchKernelGGL(k_wt,   dim3(1536),  dim3(256), 0, stream, Wq, Wk, Wv, WT);
    hipLaunchKernelGGL(k_qkv,  dim3(256),   dim3(256), 0, stream, x, WT, bq, bk, bv, Qb, Kb, VT);
    hipLaunchKernelGGL(k_stats,dim3(32, 8), dim3(256), 0, stream, Qb, Kb, mcol, rZ);
    hipLaunchKernelGGL(k_out,  dim3(32, 8), dim3(256), 0, stream, Qb, Kb, VT, mcol, rZ, out);
}

// Round 2
// 299.193 us; speedup vs baseline: 1.7958x; 1.7958x over previous
//
#include <hip/hip_runtime.h>
#include <hip/hip_bf16.h>

#define T_SEQ 2048
#define D_IN  1024
#define DH    128

typedef __attribute__((ext_vector_type(8))) short bf16x8;   // 8 bf16 in 4 VGPRs
typedef __attribute__((ext_vector_type(4))) float f32x4;

__device__ inline short f2bf(float f) {
    union { float f; unsigned u; } a; a.f = f;
    unsigned u = a.u;
    return (short)((u + 0x7fffu + ((u >> 16) & 1u)) >> 16);   // RNE
}

// ---------------- K0: W transpose -> bf16 WT[3][128][1024] ----------------
__global__ __launch_bounds__(256) void k_wt(const float* __restrict__ Wq,
                                            const float* __restrict__ Wk,
                                            const float* __restrict__ Wv,
                                            short* __restrict__ WT) {
    int idx = blockIdx.x * 256 + threadIdx.x;           // 0 .. 3*128*1024-1
    if (idx >= 3 * DH * D_IN) return;
    int m = idx >> 17;                 // which matrix
    int n = (idx >> 10) & (DH - 1);    // output col
    int k = idx & (D_IN - 1);          // input dim
    const float* W = (m == 0) ? Wq : (m == 1) ? Wk : Wv;
    WT[idx] = f2bf(W[k * DH + n]);
}

// ---------------- K1: QKV projection GEMM (bf16 MFMA) ----------------
__global__ __launch_bounds__(256) void k_qkv(const float* __restrict__ x,
                                             const short* __restrict__ WT,
                                             const float* __restrict__ bq,
                                             const float* __restrict__ bk,
                                             const float* __restrict__ bv,
                                             short* __restrict__ Qb,
                                             short* __restrict__ Kb,
                                             short* __restrict__ VT) {
    __shared__ short wlds[384 * 72];                    // 64-k chunk of WT, padded stride 72
    int tid = threadIdx.x;
    int wv  = tid >> 6;
    int lane = tid & 63;
    int lr = lane & 15, lg = lane >> 4;
    int mbase = blockIdx.x * 64 + wv * 16;

    const f32x4 z4 = {0.f, 0.f, 0.f, 0.f};
    f32x4 acc[24];
#pragma unroll
    for (int i = 0; i < 24; i++) acc[i] = z4;

    for (int kc = 0; kc < D_IN; kc += 64) {
        __syncthreads();
        for (int c = tid; c < 3072; c += 256) {
            int row = c >> 3, part = c & 7;
            *(uint4*)&wlds[row * 72 + part * 8] =
                *(const uint4*)&WT[row * 1024 + kc + part * 8];
        }
        __syncthreads();
#pragma unroll
        for (int ks2 = 0; ks2 < 2; ks2++) {
            const float* xp = x + (size_t)(mbase + lr) * D_IN + kc + ks2 * 32 + lg * 8;
            float4 x0 = *(const float4*)xp;
            float4 x1 = *(const float4*)(xp + 4);
            bf16x8 a;
            a[0] = f2bf(x0.x); a[1] = f2bf(x0.y); a[2] = f2bf(x0.z); a[3] = f2bf(x0.w);
            a[4] = f2bf(x1.x); a[5] = f2bf(x1.y); a[6] = f2bf(x1.z); a[7] = f2bf(x1.w);
#pragma unroll
            for (int nt = 0; nt < 24; nt++) {
                bf16x8 b = *(const bf16x8*)&wlds[(nt * 16 + lr) * 72 + ks2 * 32 + lg * 8];
                acc[nt] = __builtin_amdgcn_mfma_f32_16x16x32_bf16(a, b, acc[nt], 0, 0, 0);
            }
        }
    }
#pragma unroll
    for (int nt = 0; nt < 24; nt++) {
        int n = nt * 16 + lr;
        float bias = (n < 128) ? bq[n] : (n < 256) ? bk[n - 128] : bv[n - 256];
#pragma unroll
        for (int r = 0; r < 4; r++) {
            int row = mbase + lg * 4 + r;
            short v16 = f2bf(acc[nt][r] + bias);
            if (n < 128)        Qb[(size_t)row * DH + n] = v16;
            else if (n < 256)   Kb[(size_t)row * DH + (n - 128)] = v16;
            else {
                int b = row >> 11, t = row & (T_SEQ - 1), vc = n - 256;
                VT[((size_t)b * DH + vc) * T_SEQ + t] = v16;
            }
        }
    }
}

// ---- K2: per-column partial (m,Z) over a 512-wide q chunk, j-tile 64 -----
// grid (32 jb, 4 qs, 8 b). partial[b][qs][j].
__global__ __launch_bounds__(256) void k_stats(const short* __restrict__ Qb,
                                               const short* __restrict__ Kb,
                                               float* __restrict__ m_part,
                                               float* __restrict__ Z_part) {
    __shared__ short qlds[64 * 136];                    // 64 q rows, padded stride 136
    int jb = blockIdx.x, qs = blockIdx.y, b = blockIdx.z;
    int tile0 = jb * 64;
    if (qs * 512 > tile0 + 63) return;                  // no q<=j in this chunk

    int tid = threadIdx.x;
    int wv = tid >> 6, lane = tid & 63;
    int lr = lane & 15, lg = lane >> 4;
    int jsub = tile0 + wv * 16;

    const short* Kp = Kb + ((size_t)b * T_SEQ + jsub + lr) * DH;
    bf16x8 kf[4];
#pragma unroll
    for (int ks = 0; ks < 4; ks++) kf[ks] = *(const bf16x8*)(Kp + ks * 32 + lg * 8);

    float m_run[4], Z_run[4];
#pragma unroll
    for (int r = 0; r < 4; r++) { m_run[r] = -1e30f; Z_run[r] = 0.f; }

    const short* Qbase = Qb + (size_t)b * T_SEQ * DH;
    const f32x4 z4 = {0.f, 0.f, 0.f, 0.f};
    int q_lo = qs * 512;
    int q_hi = min(q_lo + 512, tile0 + 64);             // both multiples of 64

    int srow = tid >> 2, spart = tid & 3;
    for (int q0 = q_lo; q0 < q_hi; q0 += 64) {
        __syncthreads();
        {   // stage Q[q0:q0+64][0:128] -> qlds (64B per thread)
            const uint4* src = (const uint4*)(Qbase + (size_t)(q0 + srow) * DH + spart * 32);
            uint4* dst = (uint4*)&qlds[srow * 136 + spart * 32];
            uint4 a0 = src[0], a1 = src[1], a2 = src[2], a3 = src[3];
            dst[0] = a0; dst[1] = a1; dst[2] = a2; dst[3] = a3;
        }
        __syncthreads();
#pragma unroll
        for (int qt2 = 0; qt2 < 4; qt2++) {
            f32x4 s = z4;
#pragma unroll
            for (int ks = 0; ks < 4; ks++) {
                bf16x8 qf = *(const bf16x8*)&qlds[(qt2 * 16 + lr) * 136 + ks * 32 + lg * 8];
                s = __builtin_amdgcn_mfma_f32_16x16x32_bf16(kf[ks], qf, s, 0, 0, 0);
            }
            int q = q0 + qt2 * 16 + lr;
#pragma unroll
            for (int r = 0; r < 4; r++) {
                int j = jsub + lg * 4 + r;              // D row = j, col = q
                float svm = (q <= j) ? s[r] : -2e30f;
                float mn = fmaxf(m_run[r], svm);
                Z_run[r] = Z_run[r] * __expf(m_run[r] - mn) + __expf(svm - mn);
                m_run[r] = mn;
            }
        }
    }
    // merge the 16 q-sublanes (lr dim) once
#pragma unroll
    for (int r = 0; r < 4; r++) {
        float mm = m_run[r], zz = Z_run[r];
        for (int o = 1; o < 16; o <<= 1) {
            float om = __shfl_xor(mm, o, 16);
            float oz = __shfl_xor(zz, o, 16);
            float mn = fmaxf(mm, om);
            zz = zz * __expf(mm - mn) + oz * __expf(om - mn);
            mm = mn;
        }
        if (lr == 0) {
            int j = jsub + lg * 4 + r;
            size_t idx = ((size_t)b * 4 + qs) * T_SEQ + j;
            m_part[idx] = mm;
            Z_part[idx] = zz;
        }
    }
}

// ---------------- K2b: merge partials -> mcol, 1/Z ----------------
__global__ __launch_bounds__(256) void k_sred(const float* __restrict__ m_part,
                                              const float* __restrict__ Z_part,
                                              float* __restrict__ mcol,
                                              float* __restrict__ rZcol) {
    int idx = blockIdx.x * 256 + threadIdx.x;           // b*2048 + j
    int b = idx >> 11, j = idx & (T_SEQ - 1);
    int ns = j / 512 + 1;
    float m = -1e30f, Z = 0.f;
    for (int qs = 0; qs < ns; qs++) {
        size_t p = ((size_t)b * 4 + qs) * T_SEQ + j;
        float mp = m_part[p], zp = Z_part[p];
        float mn = fmaxf(m, mp);
        Z = Z * __expf(m - mn) + zp * __expf(mp - mn);
        m = mn;
    }
    mcol[idx] = m;
    rZcol[idx] = 1.0f / Z;
}

// ---- K3: out[q][v] += sum_{j in chunk, j>=q} exp(s-m[j])/Z[j] * V[j][v] ---
// grid (32 qb, 4 js, 8 b), atomicAdd into zeroed out.
__global__ __launch_bounds__(256) void k_out(const short* __restrict__ Qb,
                                             const short* __restrict__ Kb,
                                             const short* __restrict__ VT,
                                             const float* __restrict__ mcol,
                                             const float* __restrict__ rZcol,
                                             float* __restrict__ out) {
    __shared__ short klds[32 * 136];                    // K tile, padded
    __shared__ short vlds[128 * 40];                    // VT tile, padded
    __shared__ short pbuf[4][16 * 40];                  // per-wave P tile
    int qb = blockIdx.x, js = blockIdx.y, b = blockIdx.z;
    int jstart = max(js * 512, qb * 64);
    int jend = (js + 1) * 512;
    if (jstart >= jend) return;

    int tid = threadIdx.x;
    int wv = tid >> 6, lane = tid & 63;
    int lr = lane & 15, lg = lane >> 4;
    int qsub = qb * 64 + wv * 16;

    const short* Qp = Qb + ((size_t)b * T_SEQ + qsub + lr) * DH;
    bf16x8 qf[4];
#pragma unroll
    for (int ks = 0; ks < 4; ks++) qf[ks] = *(const bf16x8*)(Qp + ks * 32 + lg * 8);

    const f32x4 z4 = {0.f, 0.f, 0.f, 0.f};
    f32x4 oacc[8];
#pragma unroll
    for (int i = 0; i < 8; i++) oacc[i] = z4;

    const short* Kbase = Kb + (size_t)b * T_SEQ * DH;
    const short* VTb   = VT + (size_t)b * DH * T_SEQ;
    const float* mb = mcol + (size_t)b * T_SEQ;
    const float* zb = rZcol + (size_t)b * T_SEQ;
    short* pw = &pbuf[wv][0];

    int krow = tid >> 3, kpart = tid & 7;               // K stage mapping
    int vrow = tid >> 1, vhalf = tid & 1;               // VT stage mapping

    for (int j0 = jstart; j0 < jend; j0 += 32) {
        __syncthreads();
        {   // stage K[j0:j0+32][0:128]
            const uint4* ks_ = (const uint4*)(Kbase + (size_t)(j0 + krow) * DH + kpart * 16);
            uint4 a0 = ks_[0], a1 = ks_[1];
            uint4* kd = (uint4*)&klds[krow * 136 + kpart * 16];
            kd[0] = a0; kd[1] = a1;
            // stage VT[0:128][j0:j0+32]
            const uint4* vs = (const uint4*)(VTb + (size_t)vrow * T_SEQ + j0 + vhalf * 16);
            uint4 b0 = vs[0], b1 = vs[1];
            uint4* vd = (uint4*)&vlds[vrow * 40 + vhalf * 16];
            vd[0] = b0; vd[1] = b1;
        }
        __syncthreads();
#pragma unroll
        for (int half = 0; half < 2; half++) {
            f32x4 s = z4;
#pragma unroll
            for (int ks = 0; ks < 4; ks++) {
                bf16x8 kfr = *(const bf16x8*)&klds[(half * 16 + lr) * 136 + ks * 32 + lg * 8];
                s = __builtin_amdgcn_mfma_f32_16x16x32_bf16(qf[ks], kfr, s, 0, 0, 0);
            }
            int j = j0 + half * 16 + lr;                // D row = q, col = j
            float mj = mb[j], rz = zb[j];
#pragma unroll
            for (int r = 0; r < 4; r++) {
                int q = qsub + lg * 4 + r;
                float p = (j >= q) ? __expf(s[r] - mj) * rz : 0.f;
                pw[(lg * 4 + r) * 40 + half * 16 + lr] = f2bf(p);
            }
        }
        bf16x8 bp = *(const bf16x8*)&pw[lr * 40 + lg * 8];
#pragma unroll
        for (int vt = 0; vt < 8; vt++) {
            bf16x8 av = *(const bf16x8*)&vlds[(vt * 16 + lr) * 40 + lg * 8];
            oacc[vt] = __builtin_amdgcn_mfma_f32_16x16x32_bf16(av, bp, oacc[vt], 0, 0, 0);
        }
    }
    // accumulate: lane holds outT[v = vt*16+lg*4+r][q = qsub+lr]
#pragma unroll
    for (int vt = 0; vt < 8; vt++)
#pragma unroll
        for (int r = 0; r < 4; r++) {
            int v = vt * 16 + lg * 4 + r;
            int q = qsub + lr;
            atomicAdd(&out[((size_t)b * T_SEQ + q) * DH + v], oacc[vt][r]);
        }
}

extern "C" void kernel_launch(void* const* d_in, const int* in_sizes, int n_in,
                              void* d_out, int out_size, void* d_ws, size_t ws_size,
                              hipStream_t stream) {
    const float* x  = (const float*)d_in[0];
    const float* Wq = (const float*)d_in[1];
    const float* bq = (const float*)d_in[2];
    const float* Wk = (const float*)d_in[3];
    const float* bk = (const float*)d_in[4];
    const float* Wv = (const float*)d_in[5];
    const float* bv = (const float*)d_in[6];
    float* out = (float*)d_out;

    char* ws = (char*)d_ws;
    short* WT = (short*)ws;                                   // 768 KB
    short* Qb = (short*)(ws + 786432);                        // 4 MB
    short* Kb = (short*)(ws + 786432 + 4194304);              // 4 MB
    short* VT = (short*)(ws + 786432 + 2 * 4194304);          // 4 MB
    float* m_part = (float*)(ws + 786432 + 3 * 4194304);      // 256 KB
    float* Z_part = (float*)(ws + 786432 + 3 * 4194304 + 262144);
    float* mcol = (float*)(ws + 786432 + 3 * 4194304 + 2 * 262144);
    float* rZ   = (float*)(ws + 786432 + 3 * 4194304 + 2 * 262144 + 65536);

    hipMemsetAsync(out, 0, (size_t)out_size * sizeof(float), stream);
    hipLaunchKernelGGL(k_wt,   dim3(1536),      dim3(256), 0, stream, Wq, Wk, Wv, WT);
    hipLaunchKernelGGL(k_qkv,  dim3(256),       dim3(256), 0, stream, x, WT, bq, bk, bv, Qb, Kb, VT);
    hipLaunchKernelGGL(k_stats,dim3(32, 4, 8),  dim3(256), 0, stream, Qb, Kb, m_part, Z_part);
    hipLaunchKernelGGL(k_sred, dim3(64),        dim3(256), 0, stream, m_part, Z_part, mcol, rZ);
    hipLaunchKernelGGL(k_out,  dim3(32, 4, 8),  dim3(256), 0, stream, Qb, Kb, VT, mcol, rZ, out);
}